// Round 1
// baseline (67.672 us; speedup 1.0000x reference)
//
#include <hip/hip_runtime.h>

// LDS_84104049590333: diagonal linear SSM + short FIR == one causal conv.
// out[b,t] = sum_{d=0}^{t} K[d] * x[b,t-d]
//   K[d] = sum_s C[s]*Bp[s]*A[s]^d, plus M[d] for d<5.
// Kernel 1 builds K (1024 floats) into d_ws; kernel 2 is a tiled Toeplitz conv.

#define T_LEN 1024
#define BSZ_N 896
#define S_DIM 256
#define KX_N  5
#define TBLK  512          // time-tile per block (64 lanes x 8 outputs)
#define NTB   (T_LEN / TBLK)
#define XS_LEN 1544        // window [t0-1028, t0+TBLK-1] = 1540 floats, +4 pad/align

__global__ __launch_bounds__(256)
void k_build(const float* __restrict__ A,
             const float* __restrict__ Bp,
             const float* __restrict__ C,
             const float* __restrict__ M,
             float* __restrict__ Kg) {
    int d = blockIdx.x * 256 + threadIdx.x;
    if (d >= T_LEN) return;
    float fd = (float)d;
    float acc = 0.f;
    for (int s = 0; s < S_DIM; ++s) {
        float w = C[s] * Bp[s];
        // A in (e^-5, 1]; A^d via exp2/log2 (fp32-accurate; relative err ~1e-6)
        float ad = exp2f(fd * log2f(A[s]));
        acc = fmaf(w, ad, acc);
    }
    if (d < KX_N) acc += M[d];
    Kg[d] = acc;
}

__global__ __launch_bounds__(64)
void k_conv(const float* __restrict__ x,
            const float* __restrict__ Kg,
            float* __restrict__ out) {
    __shared__ __align__(16) float xs[XS_LEN];
    const int tb  = blockIdx.x;          // 0..NTB-1
    const int b   = blockIdx.y;          // 0..BSZ_N-1
    const int tid = threadIdx.x;         // 0..63
    const int t0  = tb * TBLK;
    const int dmax = (t0 + TBLK - 1 < T_LEN - 1) ? (t0 + TBLK - 1) : (T_LEN - 1);

    // Stage x window: xs[i] = x[b, t0-1028+i], zero outside [0,T).
    const float* xb = x + b * T_LEN;
    const int tau0 = t0 - 1028;
    for (int i = tid; i < XS_LEN; i += 64) {
        int tau = tau0 + i;
        xs[i] = (tau >= 0 && tau < T_LEN) ? xb[tau] : 0.f;
    }
    __syncthreads();

    // Each lane computes t = t0 + tid*8 + tt, tt in [0,8).
    // x[b, t-d] lives at xs[xbase + (tt - j)] with xbase = 1028 + tid*8 - d4,
    // d = d4 + j. Sliding 12-float register window over xs; one new b128/iter.
    float acc[8];
#pragma unroll
    for (int k = 0; k < 8; ++k) acc[k] = 0.f;

    const int xb0 = 1028 + tid * 8;      // xbase at d4 = 0 (multiple of 4)
    float w[12];                          // w[o+4] = xs[xbase + o], o in [-4, 7]
    {
        float4 W1 = *(const float4*)&xs[xb0];
        float4 W2 = *(const float4*)&xs[xb0 + 4];
        w[4] = W1.x; w[5] = W1.y; w[6]  = W1.z; w[7]  = W1.w;
        w[8] = W2.x; w[9] = W2.y; w[10] = W2.z; w[11] = W2.w;
    }
    for (int d4 = 0; d4 <= dmax; d4 += 4) {
        // K is wave-uniform -> scalar load (L1/sL1 cached)
        const float4 kv4 = *(const float4*)(Kg + d4);
        const float kv[4] = {kv4.x, kv4.y, kv4.z, kv4.w};
        const float4 nw = *(const float4*)&xs[xb0 - d4 - 4];  // new o = [-4,-1]
        w[0] = nw.x; w[1] = nw.y; w[2] = nw.z; w[3] = nw.w;
#pragma unroll
        for (int tt = 0; tt < 8; ++tt) {
#pragma unroll
            for (int j = 0; j < 4; ++j) {
                acc[tt] = fmaf(kv[j], w[tt - j + 4], acc[tt]);
            }
        }
        // shift window: next iter's o+4 block is this iter's o block
#pragma unroll
        for (int k = 11; k >= 4; --k) w[k] = w[k - 4];
    }

    const int obase = b * T_LEN + t0 + tid * 8;
    float4 o0 = {acc[0], acc[1], acc[2], acc[3]};
    float4 o1 = {acc[4], acc[5], acc[6], acc[7]};
    *(float4*)&out[obase]     = o0;
    *(float4*)&out[obase + 4] = o1;
}

extern "C" void kernel_launch(void* const* d_in, const int* in_sizes, int n_in,
                              void* d_out, int out_size, void* d_ws, size_t ws_size,
                              hipStream_t stream) {
    const float* x  = (const float*)d_in[0];  // (896,1024,1)
    const float* A  = (const float*)d_in[1];  // (256,)
    const float* Bp = (const float*)d_in[2];  // (1,256)
    const float* C  = (const float*)d_in[3];  // (256,1)
    const float* M  = (const float*)d_in[4];  // (1,1,5)
    // d_in[5] = h0, all zeros -> folded into the closed form
    float* out = (float*)d_out;               // (896,1024,1) fp32
    float* Kg  = (float*)d_ws;                // 1024 floats of scratch

    k_build<<<dim3(T_LEN / 256), dim3(256), 0, stream>>>(A, Bp, C, M, Kg);
    k_conv<<<dim3(NTB, BSZ_N), dim3(64), 0, stream>>>(x, Kg, out);
}

// Round 2
// 33.740 us; speedup vs baseline: 2.0057x; 2.0057x over previous
//
#include <hip/hip_runtime.h>

// LDS_84104049590333: diagonal linear SSM + short FIR == one causal conv.
// out[b,t] = sum_{d=0}^{t} K[d]*x[b,t-d],  K[d] = sum_s C[s]*Bp[s]*A[s]^d (+ M[d], d<5)
//
// k_build: 1024 blocks (one per d) x 256 threads (one per state), shuffle+LDS reduce.
// k_conv : tiled causal Toeplitz conv. TBLK=512 outputs/block, 4 waves/block with the
//          d-range split across waves (LDS partial-sum reduce at the end).
//          Inner loop: K-step of 8, sliding 16-float register window held as two
//          float4 pairs with unroll-2 name rotation (zero shift-movs), one pair of
//          ds_read_b128 per 8 d's. LDS is XOR-swizzled at 16B-chunk granularity
//          (u ^= (u>>3)&7) on BOTH the staging writes and the window reads to break
//          the 16-way bank conflict of the 32B lane stride.

#define T_LEN 1024
#define BSZ_N 896
#define S_DIM 256
#define KX_N  5
#define TBLK  512
#define NTB   (T_LEN / TBLK)     // 2
#define XS_CHUNKS 392            // 1568 floats; window needs [t0-1032, t0+512), mult of 8
#define RED_WAVES 3

__device__ __forceinline__ int swz(int u) { return u ^ ((u >> 3) & 7); }

#define CSEL(v, c) ((c)==0?(v).x:((c)==1?(v).y:((c)==2?(v).z:(v).w)))

// One K-step of 8 d's: fresh pair (F0,F1) = xs[i_base-8 .. i_base-1] (e in [-8,-1]),
// prev pair (P0,P1) = xs[i_base .. i_base+7] (e in [0,7]);  e = tt - j.
#define FMA_STEP(F0,F1,P0,P1,KA,KB) do {                                         \
    const float kv[8] = {(KA).x,(KA).y,(KA).z,(KA).w,(KB).x,(KB).y,(KB).z,(KB).w};\
    _Pragma("unroll")                                                             \
    for (int tt = 0; tt < 8; ++tt) {                                              \
        _Pragma("unroll")                                                         \
        for (int j = 0; j < 8; ++j) {                                             \
            const int e = tt - j;                                                 \
            const float xv = (e >= 4) ? CSEL(P1, e-4)                             \
                           : (e >= 0) ? CSEL(P0, e)                               \
                           : (e >= -4) ? CSEL(F1, e+4)                            \
                           : CSEL(F0, e+8);                                       \
            acc[tt] = fmaf(kv[j], xv, acc[tt]);                                   \
        }                                                                         \
    }                                                                             \
} while (0)

__global__ __launch_bounds__(256)
void k_build(const float* __restrict__ A, const float* __restrict__ Bp,
             const float* __restrict__ C, const float* __restrict__ M,
             float* __restrict__ Kg) {
    const int d = blockIdx.x;          // 0..1023
    const int s = threadIdx.x;         // 0..255
    const float w = C[s] * Bp[s];
    const float ad = exp2f((float)d * log2f(A[s]));   // A in (e^-5, 1], exact enough
    float v = w * ad;
#pragma unroll
    for (int off = 1; off < 64; off <<= 1) v += __shfl_xor(v, off, 64);
    __shared__ float part[4];
    const int wave = threadIdx.x >> 6;
    const int lane = threadIdx.x & 63;
    if (lane == 0) part[wave] = v;
    __syncthreads();
    if (threadIdx.x == 0) {
        float r = part[0] + part[1] + part[2] + part[3];
        if (d < KX_N) r += M[d];
        Kg[d] = r;
    }
}

__global__ __launch_bounds__(256)
void k_conv(const float* __restrict__ x, const float* __restrict__ Kg,
            float* __restrict__ out) {
    __shared__ __align__(16) float xs[XS_CHUNKS * 4];
    __shared__ __align__(16) float red[RED_WAVES][64][9];   // +1 pad: conflict-free
    const int tb  = (NTB - 1) - blockIdx.x;   // heavy tile (tb=1) dispatches first
    const int b   = blockIdx.y;
    const int t0  = tb * TBLK;
    const int tid = threadIdx.x;
    const int wave = tid >> 6, lane = tid & 63;

    // ---- stage x window: xs[i] = x[b, t0-1032+i] (zero outside [0,T)), swizzled
    const float* xb = x + b * T_LEN;
    const int tau0 = t0 - 1032;
    for (int j = tid; j < XS_CHUNKS; j += 256) {
        const int tau = tau0 + 4 * j;
        float4 v = make_float4(0.f, 0.f, 0.f, 0.f);
        if ((unsigned)tau < (unsigned)T_LEN) v = *(const float4*)(xb + tau);
        *(float4*)(xs + 4 * swz(j)) = v;
    }
    __syncthreads();

    // ---- each lane: outputs t = t0 + 8*lane + tt, tt in [0,8)
    // d = 8q + j; x[t-d] = xs[i_base(q) + tt - j], i_base(q) = 1032 + 8*lane - 8*q.
    // Wave w handles q in [w*n, (w+1)*n), n = ((t0+TBLK)/8)/4 (16 or 32, even).
    float acc[8];
#pragma unroll
    for (int k = 0; k < 8; ++k) acc[k] = 0.f;

    const int Cq = (t0 + TBLK) / 8;
    const int n  = Cq / 4;
    const int q0 = wave * n;
    const int ubase = 256 + 2 * lane;          // fresh chunk index at q=0 would be ubase

    float4 y0, y1;                              // "prev" pair entering the loop
    {
        const int u = ubase - 2 * q0 + 2;       // chunks covering e in [0,7] at q0
        const int ba = swz(u) << 4;
        y0 = *(const float4*)((const char*)xs + ba);
        y1 = *(const float4*)((const char*)xs + (ba ^ 16));   // u even -> partner = ba^16
    }

    for (int q = q0; q < q0 + n; q += 2) {
        // step A: d-base = 8q; fresh = chunks (ubase-2q, +1)
        float4 f0, f1;
        {
            const int u = ubase - 2 * q;
            const int ba = swz(u) << 4;
            f0 = *(const float4*)((const char*)xs + ba);
            f1 = *(const float4*)((const char*)xs + (ba ^ 16));
        }
        {
            const float4 ka = *(const float4*)(Kg + 8 * q);
            const float4 kb = *(const float4*)(Kg + 8 * q + 4);
            FMA_STEP(f0, f1, y0, y1, ka, kb);
        }
        // step B: d-base = 8(q+1); fresh = chunks (ubase-2q-2, +1); prev = F
        {
            const int u = ubase - 2 * q - 2;
            const int ba = swz(u) << 4;
            y0 = *(const float4*)((const char*)xs + ba);
            y1 = *(const float4*)((const char*)xs + (ba ^ 16));
        }
        {
            const float4 ka = *(const float4*)(Kg + 8 * q + 8);
            const float4 kb = *(const float4*)(Kg + 8 * q + 12);
            FMA_STEP(y0, y1, f0, f1, ka, kb);
        }
    }

    // ---- reduce the 4 per-wave partials, wave 0 stores
    if (wave != 0) {
#pragma unroll
        for (int k = 0; k < 8; ++k) red[wave - 1][lane][k] = acc[k];
    }
    __syncthreads();
    if (wave == 0) {
#pragma unroll
        for (int w = 0; w < RED_WAVES; ++w)
#pragma unroll
            for (int k = 0; k < 8; ++k) acc[k] += red[w][lane][k];
        float* op = out + b * T_LEN + t0 + 8 * lane;
        float4 o0 = {acc[0], acc[1], acc[2], acc[3]};
        float4 o1 = {acc[4], acc[5], acc[6], acc[7]};
        *(float4*)op       = o0;
        *(float4*)(op + 4) = o1;
    }
}

extern "C" void kernel_launch(void* const* d_in, const int* in_sizes, int n_in,
                              void* d_out, int out_size, void* d_ws, size_t ws_size,
                              hipStream_t stream) {
    const float* x  = (const float*)d_in[0];  // (896,1024,1) fp32
    const float* A  = (const float*)d_in[1];  // (256,)
    const float* Bp = (const float*)d_in[2];  // (1,256)
    const float* C  = (const float*)d_in[3];  // (256,1)
    const float* M  = (const float*)d_in[4];  // (1,1,5)
    // d_in[5] = h0 == 0, folded into the closed form
    float* out = (float*)d_out;               // (896,1024,1) fp32
    float* Kg  = (float*)d_ws;                // 1024 floats scratch

    k_build<<<dim3(T_LEN), dim3(S_DIM), 0, stream>>>(A, Bp, C, M, Kg);
    k_conv<<<dim3(NTB, BSZ_N), dim3(256), 0, stream>>>(x, Kg, out);
}

// Round 3
// 31.917 us; speedup vs baseline: 2.1202x; 1.0571x over previous
//
#include <hip/hip_runtime.h>

// LDS_84104049590333: diagonal linear SSM + short FIR == one causal conv.
// out[b,t] = sum_{d=0}^{t} K[d]*x[b,t-d],  K[d] = sum_s C[s]*Bp[s]*A[s]^d (+ M[d], d<5)
//
// k_build: 1024 blocks (one per d) x 256 threads (one per state), shuffle+LDS reduce.
// k_conv : tiled causal Toeplitz conv. TBLK=512 outputs/block, 4 waves/block, d-range
//          split across waves (LDS partial-sum reduce at the end).
//          Inner loop: 4 q-steps (32 d's) per iteration, sliding register window with
//          explicit name rotation (P->A->B->C->D, zero shift-movs). All 8 ds_read_b128
//          issue at the top of the iteration. K taps are loaded through a
//          readfirstlane-derived scalar base -> s_load into SGPRs (no VMEM latency in
//          the vector domain). LDS XOR-swizzled at 16B-chunk granularity on both the
//          staging writes and window reads (breaks the 32B-lane-stride 16-way conflict;
//          residual 2-way is free per m136).

#define T_LEN 1024
#define BSZ_N 896
#define S_DIM 256
#define KX_N  5
#define TBLK  512
#define NTB   (T_LEN / TBLK)     // 2
#define XS_CHUNKS 392            // 1568 floats: window [t0-1032, t0+536)
#define RED_WAVES 3

__device__ __forceinline__ int swz(int u) { return u ^ ((u >> 3) & 7); }

#define CSEL(v, c) ((c)==0?(v).x:((c)==1?(v).y:((c)==2?(v).z:(v).w)))

// One K-step of 8 d's: fresh pair (F0,F1) = xs chunks covering e in [-8,-1],
// prev pair (P0,P1) = e in [0,7]; e = tt - j; d = dbase + j.
#define FMA_STEP(F0,F1,P0,P1,KA,KB) do {                                         \
    const float kv[8] = {(KA).x,(KA).y,(KA).z,(KA).w,(KB).x,(KB).y,(KB).z,(KB).w};\
    _Pragma("unroll")                                                             \
    for (int tt = 0; tt < 8; ++tt) {                                              \
        _Pragma("unroll")                                                         \
        for (int j = 0; j < 8; ++j) {                                             \
            const int e = tt - j;                                                 \
            const float xv = (e >= 4) ? CSEL(P1, e-4)                             \
                           : (e >= 0) ? CSEL(P0, e)                               \
                           : (e >= -4) ? CSEL(F1, e+4)                            \
                           : CSEL(F0, e+8);                                       \
            acc[tt] = fmaf(kv[j], xv, acc[tt]);                                   \
        }                                                                         \
    }                                                                             \
} while (0)

// Load the chunk pair (u, u+1) from swizzled LDS. u is always even; partner
// address = base ^ 16 (XOR of bit0 of the chunk index).
#define LOAD_PAIR(D0, D1, U) do {                                                 \
    const int ba_ = swz(U) << 4;                                                  \
    D0 = *(const float4*)((const char*)xs + ba_);                                 \
    D1 = *(const float4*)((const char*)xs + (ba_ ^ 16));                          \
} while (0)

__global__ __launch_bounds__(256)
void k_build(const float* __restrict__ A, const float* __restrict__ Bp,
             const float* __restrict__ C, const float* __restrict__ M,
             float* __restrict__ Kg) {
    const int d = blockIdx.x;          // 0..1023
    const int s = threadIdx.x;         // 0..255
    const float w = C[s] * Bp[s];
    const float ad = exp2f((float)d * log2f(A[s]));   // A in (e^-5, 1]
    float v = w * ad;
#pragma unroll
    for (int off = 1; off < 64; off <<= 1) v += __shfl_xor(v, off, 64);
    __shared__ float part[4];
    const int wave = threadIdx.x >> 6;
    const int lane = threadIdx.x & 63;
    if (lane == 0) part[wave] = v;
    __syncthreads();
    if (threadIdx.x == 0) {
        float r = part[0] + part[1] + part[2] + part[3];
        if (d < KX_N) r += M[d];
        Kg[d] = r;
    }
}

__global__ __launch_bounds__(256)
void k_conv(const float* __restrict__ x, const float* __restrict__ Kg,
            float* __restrict__ out) {
    __shared__ __align__(16) float xs[XS_CHUNKS * 4];
    __shared__ __align__(16) float red[RED_WAVES][64][9];   // +1 pad: conflict-free
    const int tb  = (NTB - 1) - blockIdx.x;   // heavy tile (tb=1) dispatches first
    const int b   = blockIdx.y;
    const int t0  = tb * TBLK;
    const int tid = threadIdx.x;
    const int wave = tid >> 6, lane = tid & 63;

    // ---- stage x window: xs[i] = x[b, t0-1032+i] (zero outside [0,T)), swizzled
    const float* xb = x + b * T_LEN;
    const int tau0 = t0 - 1032;
    for (int j = tid; j < XS_CHUNKS; j += 256) {
        const int tau = tau0 + 4 * j;
        float4 v = make_float4(0.f, 0.f, 0.f, 0.f);
        if ((unsigned)tau < (unsigned)T_LEN) v = *(const float4*)(xb + tau);
        *(float4*)(xs + 4 * swz(j)) = v;
    }
    __syncthreads();

    // ---- lane computes t = t0 + 8*lane + tt, tt in [0,8)
    // d = 8q + j; x[t-d] = xs[1032 + 8*lane - 8q + tt - j].
    // Wave w handles q in [w*n, (w+1)*n), n = Cq/4; iterate 4 q's at a time.
    float acc[8];
#pragma unroll
    for (int k = 0; k < 8; ++k) acc[k] = 0.f;

    const int Cq  = (t0 + TBLK) / 8;
    const int n   = Cq / 4;                       // 16 (tb=0) or 32 (tb=1)
    const int n4  = n / 4;                        // 4 or 8
    const int qu0 = __builtin_amdgcn_readfirstlane(wave * n);  // wave-uniform scalar
    const float* __restrict__ Kw = Kg + 8 * qu0;  // scalar K base -> s_load
    const int ub0 = 256 + 2 * lane - 2 * qu0;     // fresh-chunk index at q = q0

    float4 p0, p1;                                // prev pair entering the loop
    LOAD_PAIR(p0, p1, ub0 + 2);

    for (int i = 0; i < n4; ++i) {
        const int ui = ub0 - 8 * i;
        const float* __restrict__ Ki = Kw + 32 * i;   // uniform -> SGPR
        float4 a0, a1, b0, b1, c0, c1, d0, d1;
        LOAD_PAIR(a0, a1, ui);
        LOAD_PAIR(b0, b1, ui - 2);
        LOAD_PAIR(c0, c1, ui - 4);
        LOAD_PAIR(d0, d1, ui - 6);
        {
            const float4 ka = *(const float4*)(Ki);
            const float4 kb = *(const float4*)(Ki + 4);
            FMA_STEP(a0, a1, p0, p1, ka, kb);
        }
        {
            const float4 ka = *(const float4*)(Ki + 8);
            const float4 kb = *(const float4*)(Ki + 12);
            FMA_STEP(b0, b1, a0, a1, ka, kb);
        }
        {
            const float4 ka = *(const float4*)(Ki + 16);
            const float4 kb = *(const float4*)(Ki + 20);
            FMA_STEP(c0, c1, b0, b1, ka, kb);
        }
        {
            const float4 ka = *(const float4*)(Ki + 24);
            const float4 kb = *(const float4*)(Ki + 28);
            FMA_STEP(d0, d1, c0, c1, ka, kb);
        }
        p0 = d0; p1 = d1;
    }

    // ---- reduce the 4 per-wave partials, wave 0 stores
    if (wave != 0) {
#pragma unroll
        for (int k = 0; k < 8; ++k) red[wave - 1][lane][k] = acc[k];
    }
    __syncthreads();
    if (wave == 0) {
#pragma unroll
        for (int w = 0; w < RED_WAVES; ++w)
#pragma unroll
            for (int k = 0; k < 8; ++k) acc[k] += red[w][lane][k];
        float* op = out + b * T_LEN + t0 + 8 * lane;
        float4 o0 = {acc[0], acc[1], acc[2], acc[3]};
        float4 o1 = {acc[4], acc[5], acc[6], acc[7]};
        *(float4*)op       = o0;
        *(float4*)(op + 4) = o1;
    }
}

extern "C" void kernel_launch(void* const* d_in, const int* in_sizes, int n_in,
                              void* d_out, int out_size, void* d_ws, size_t ws_size,
                              hipStream_t stream) {
    const float* x  = (const float*)d_in[0];  // (896,1024,1) fp32
    const float* A  = (const float*)d_in[1];  // (256,)
    const float* Bp = (const float*)d_in[2];  // (1,256)
    const float* C  = (const float*)d_in[3];  // (256,1)
    const float* M  = (const float*)d_in[4];  // (1,1,5)
    // d_in[5] = h0 == 0, folded into the closed form
    float* out = (float*)d_out;               // (896,1024,1) fp32
    float* Kg  = (float*)d_ws;                // 1024 floats scratch

    k_build<<<dim3(T_LEN), dim3(S_DIM), 0, stream>>>(A, Bp, C, M, Kg);
    k_conv<<<dim3(NTB, BSZ_N), dim3(256), 0, stream>>>(x, Kg, out);
}